// Round 1
// 1775.883 us; speedup vs baseline: 1.1032x; 1.1032x over previous
//
#include <hip/hip_runtime.h>
#include <hip/hip_bf16.h>
#include <stdint.h>

#define D_ 512
#define V_ 8192
#define B_ 2
#define T_ 256
#define U_ 64
#define M_ (B_*T_*U_)   /* 32768 rows of the big GEMM */
#define BT_ (B_*T_)     /* 512  */
#define BU_ (B_*U_)     /* 128  */

typedef __bf16 bf16x8 __attribute__((ext_vector_type(8)));
typedef float  floatx4 __attribute__((ext_vector_type(4)));

// async global->LDS, 16B per lane. LDS dst must be wave-uniform base + lane*16.
__device__ inline void load16_lds(const void* g, void* l) {
  __builtin_amdgcn_global_load_lds(
      (const __attribute__((address_space(1))) uint32_t*)(uintptr_t)g,
      (__attribute__((address_space(3))) uint32_t*)(uintptr_t)l,
      16, 0, 0);
}

// ---------------- K1: enc = v@W1+b1 (512 rows), dec = t@W2+b2 (128 rows), fp32 out
__global__ __launch_bounds__(256) void encdec_kernel(
    const float* __restrict__ v, const float* __restrict__ t,
    const float* __restrict__ W1, const float* __restrict__ b1,
    const float* __restrict__ W2, const float* __restrict__ b2,
    float* __restrict__ enc, float* __restrict__ dec) {
  __shared__ float xs[D_];
  int r = blockIdx.x;
  const float* x; const float* W; const float* bias; float* out;
  if (r < BT_) { x = v + (size_t)r*D_;          W = W1; bias = b1; out = enc + (size_t)r*D_; }
  else         { int rr = r - BT_;
                 x = t + (size_t)rr*D_;         W = W2; bias = b2; out = dec + (size_t)rr*D_; }
  int tid = threadIdx.x;
  xs[tid]       = x[tid];
  xs[tid + 256] = x[tid + 256];
  __syncthreads();
  float a0 = 0.f, a1 = 0.f;
  int c0 = tid * 2;
  #pragma unroll 8
  for (int k = 0; k < D_; ++k) {
    float xv = xs[k];
    float2 w = *(const float2*)(W + (size_t)k*D_ + c0);
    a0 += xv * w.x;
    a1 += xv * w.y;
  }
  float2 o; o.x = a0 + bias[c0]; o.y = a1 + bias[c0+1];
  *(float2*)(out + c0) = o;
}

// ---------------- K1b: WvT[n][k] = bf16(Wv[k][n])  (512x8192 -> 8192x512)
__global__ __launch_bounds__(256) void wv_transpose_kernel(
    const float* __restrict__ Wv, __bf16* __restrict__ WvT) {
  __shared__ float tile[64][65];
  int k0 = (blockIdx.x & 7) * 64;    // 512/64 = 8 k-tiles
  int n0 = (blockIdx.x >> 3) * 64;   // 8192/64 = 128 n-tiles
  int tid = threadIdx.x;
  int c  = tid & 63;
  int r0 = tid >> 6;                 // 0..3
  #pragma unroll
  for (int i = 0; i < 64; i += 4)
    tile[r0 + i][c] = Wv[(size_t)(k0 + r0 + i) * V_ + n0 + c];
  __syncthreads();
  #pragma unroll
  for (int i = 0; i < 64; i += 4)
    WvT[(size_t)(n0 + r0 + i) * D_ + k0 + c] = (__bf16)tile[c][r0 + i];
}

// ---------------- K1c: h[m][k] = bf16(relu(enc[bt][k] + dec[b*64+u][k]))
__global__ __launch_bounds__(256) void build_h_kernel(
    const float* __restrict__ enc, const float* __restrict__ dec,
    __bf16* __restrict__ h) {
  int tid = blockIdx.x * 256 + threadIdx.x;  // 0 .. 2M-1 (8 elems each)
  int m  = tid >> 6;
  int kc = (tid & 63) << 3;
  int bt = m >> 6;
  int dr = ((m >> 14) << 6) | (m & 63);
  const float4* e4 = (const float4*)(enc + (size_t)bt*D_ + kc);
  const float4* d4 = (const float4*)(dec + (size_t)dr*D_ + kc);
  float4 e0 = e4[0], e1 = e4[1];
  float4 d0 = d4[0], d1 = d4[1];
  bf16x8 o;
  o[0] = (__bf16)fmaxf(e0.x + d0.x, 0.f);
  o[1] = (__bf16)fmaxf(e0.y + d0.y, 0.f);
  o[2] = (__bf16)fmaxf(e0.z + d0.z, 0.f);
  o[3] = (__bf16)fmaxf(e0.w + d0.w, 0.f);
  o[4] = (__bf16)fmaxf(e1.x + d1.x, 0.f);
  o[5] = (__bf16)fmaxf(e1.y + d1.y, 0.f);
  o[6] = (__bf16)fmaxf(e1.z + d1.z, 0.f);
  o[7] = (__bf16)fmaxf(e1.w + d1.w, 0.f);
  *(bf16x8*)(h + (size_t)m*D_ + kc) = o;
}

// ---------------- K2: fused logits + log-softmax.
// Each block: BM=128 full rows, loops all 64 n-tiles TWICE.
// Pass 0: accumulate per-lane sum(exp(logit)) in regs (no stores, no atomics).
// Block-local reduce -> lse per row in registers.
// Pass 1: recompute MFMAs, write logit + bias - lse directly (single HBM write).
// A-tile (128x512 bf16 = 128 KB) resident in LDS, staged ONCE per block.
// B double-buffered 2x16 KB, counted vmcnt(2) + raw s_barrier (loads stay in
// flight across barriers -- avoids the __syncthreads vmcnt(0) drain).
#define BM 128
#define BN 128
#define BKk 64
#define NTILES (V_/BN)            /* 64  */
#define QTOT   (NTILES*(D_/BKk))  /* 512 B-chunks per pass */

__global__ __launch_bounds__(512) void fused_lsm_kernel(
    const __bf16* __restrict__ h, const __bf16* __restrict__ WvT,
    const float* __restrict__ bv, float* __restrict__ out) {
  __shared__ __bf16 As[BM * D_];       // 128 KB, full-K A tile (chunk-swizzled)
  __shared__ __bf16 Bs[2][BN * BKk];   // 2 x 16 KB double buffer (chunk-swizzled)

  const int tid  = threadIdx.x;
  const int lane = tid & 63;
  const int w    = tid >> 6;        // 8 waves
  const int wm   = w & 1;           // m-half (64 rows)
  const int wn   = w >> 1;          // 0..3, n-quarter (32 cols)
  const int quad = lane >> 4;
  const int l15  = lane & 15;
  const int key  = lane & 7;
  const int gm0  = blockIdx.x * BM;

  // ---- stage A once: 8192 slots of 16B; slot s holds row r=s>>6, chunk
  //      c = (sc&~7)|((sc&7)^(r&7))  (XOR swizzle via pre-swizzled global src)
  #pragma unroll
  for (int it = 0; it < 16; ++it) {
    int s  = it * 512 + tid;
    int r  = s >> 6;
    int sc = s & 63;
    int c  = (sc & ~7) | ((sc & 7) ^ (r & 7));
    load16_lds(h + (size_t)(gm0 + r) * D_ + c * 8, As + (size_t)s * 8);
  }
  // ---- stage B chunk q=0 (n=0, ki=0) into Bs[0]
  #pragma unroll
  for (int it = 0; it < 2; ++it) {
    int s = it * 512 + tid;
    int r = s >> 3;
    int c = (s & 7) ^ (r & 7);
    load16_lds(WvT + (size_t)r * D_ + c * 8, Bs[0] + s * 8);
  }
  asm volatile("s_waitcnt vmcnt(0)" ::: "memory");
  __builtin_amdgcn_s_barrier();
  asm volatile("" ::: "memory");

  float sacc[4][4];
  #pragma unroll
  for (int mt = 0; mt < 4; ++mt)
    #pragma unroll
    for (int i = 0; i < 4; ++i) sacc[mt][i] = 0.f;
  float lseR[4][4];

  for (int pass = 0; pass < 2; ++pass) {
    for (int n = 0; n < NTILES; ++n) {
      floatx4 acc[4][2];
      #pragma unroll
      for (int mt = 0; mt < 4; ++mt)
        #pragma unroll
        for (int nt = 0; nt < 2; ++nt)
          acc[mt][nt] = (floatx4){0.f, 0.f, 0.f, 0.f};

      for (int ki = 0; ki < 8; ++ki) {
        const int q   = n * 8 + ki;
        const int cur = q & 1;
        if (!(pass == 1 && q == QTOT - 1)) {
          // prefetch next B chunk (wraps pass0->pass1 at q=511 -> q=0)
          const int qq = (q + 1) & (QTOT - 1);
          const int nn = qq >> 3, kn = qq & 7;
          #pragma unroll
          for (int it = 0; it < 2; ++it) {
            int s = it * 512 + tid;
            int r = s >> 3;
            int c = (s & 7) ^ (r & 7);
            load16_lds(WvT + (size_t)(nn * BN + r) * D_ + kn * BKk + c * 8,
                       Bs[cur ^ 1] + s * 8);
          }
          // wait only for the CURRENT chunk's loads (oldest); keep the 2 newest
          // (next chunk) in flight across the barrier.
          asm volatile("s_waitcnt vmcnt(2)" ::: "memory");
        } else {
          asm volatile("s_waitcnt vmcnt(0)" ::: "memory");
        }
        __builtin_amdgcn_s_barrier();
        asm volatile("" ::: "memory");

        const __bf16* bcur = &Bs[cur][0];
        #pragma unroll
        for (int kk = 0; kk < 2; ++kk) {
          bf16x8 af[4], bfr[2];
          const int cA = ki * 8 + kk * 4 + quad;
          const int sA = (cA & ~7) | ((cA & 7) ^ key);
          #pragma unroll
          for (int mt = 0; mt < 4; ++mt) {
            int r = wm * 64 + mt * 16 + l15;
            af[mt] = *(const bf16x8*)(As + (size_t)(r * 64 + sA) * 8);
          }
          const int sB = (kk * 4 + quad) ^ key;
          #pragma unroll
          for (int nt = 0; nt < 2; ++nt) {
            int r = wn * 32 + nt * 16 + l15;
            bfr[nt] = *(const bf16x8*)(bcur + (size_t)(r * 8 + sB) * 8);
          }
          #pragma unroll
          for (int mt = 0; mt < 4; ++mt)
            #pragma unroll
            for (int nt = 0; nt < 2; ++nt)
              acc[mt][nt] = __builtin_amdgcn_mfma_f32_16x16x32_bf16(
                  af[mt], bfr[nt], acc[mt][nt], 0, 0, 0);
        }
        asm volatile("" ::: "memory");
        __builtin_amdgcn_s_barrier();   // all waves done reading Bs[cur] before
                                        // it is overwritten at iter q+2's stage
      }

      float bvv[2];
      #pragma unroll
      for (int nt = 0; nt < 2; ++nt)
        bvv[nt] = bv[n * BN + wn * 32 + nt * 16 + l15];

      if (pass == 0) {
        // accumulate per-lane partial sum(exp) across all n-tiles
        #pragma unroll
        for (int mt = 0; mt < 4; ++mt)
          #pragma unroll
          for (int i = 0; i < 4; ++i) {
            float s = sacc[mt][i];
            #pragma unroll
            for (int nt = 0; nt < 2; ++nt)
              s += exp2f((acc[mt][nt][i] + bvv[nt]) * 1.44269504088896f);
            sacc[mt][i] = s;
          }
      } else {
        #pragma unroll
        for (int mt = 0; mt < 4; ++mt)
          #pragma unroll
          for (int i = 0; i < 4; ++i) {
            const int row = gm0 + wm * 64 + mt * 16 + quad * 4 + i;
            const float l = lseR[mt][i];
            #pragma unroll
            for (int nt = 0; nt < 2; ++nt)
              out[(size_t)row * V_ + n * BN + wn * 32 + nt * 16 + l15] =
                  acc[mt][nt][i] + bvv[nt] - l;
          }
      }
    }

    if (pass == 0) {
      // --- block-local LSE: butterfly across the 16 l15 lanes (quad-preserving)
      #pragma unroll
      for (int mt = 0; mt < 4; ++mt)
        #pragma unroll
        for (int i = 0; i < 4; ++i) {
          float s = sacc[mt][i];
          s += __shfl_xor(s, 1, 64);
          s += __shfl_xor(s, 2, 64);
          s += __shfl_xor(s, 4, 64);
          s += __shfl_xor(s, 8, 64);
          sacc[mt][i] = s;
        }
      __syncthreads();
      // Bs[1] is free here (q=511 computed from Bs[1]; prefetch went to Bs[0]).
      float* scr = (float*)&Bs[1][0];   // scr[wn][row], 4*128 floats = 2 KB
      if (l15 == 0) {
        #pragma unroll
        for (int mt = 0; mt < 4; ++mt)
          #pragma unroll
          for (int i = 0; i < 4; ++i)
            scr[wn * 128 + wm * 64 + mt * 16 + quad * 4 + i] = sacc[mt][i];
      }
      __syncthreads();
      #pragma unroll
      for (int mt = 0; mt < 4; ++mt)
        #pragma unroll
        for (int i = 0; i < 4; ++i) {
          int r = wm * 64 + mt * 16 + quad * 4 + i;
          lseR[mt][i] = logf(scr[r] + scr[128 + r] + scr[256 + r] + scr[384 + r]);
        }
      __syncthreads();   // scratch consumed before pass-1 stage overwrites Bs[1]
    }
  }
}

extern "C" void kernel_launch(void* const* d_in, const int* in_sizes, int n_in,
                              void* d_out, int out_size, void* d_ws, size_t ws_size,
                              hipStream_t stream) {
  const float* v  = (const float*)d_in[0];
  const float* t  = (const float*)d_in[1];
  const float* W1 = (const float*)d_in[2];
  const float* b1 = (const float*)d_in[3];
  const float* W2 = (const float*)d_in[4];
  const float* b2 = (const float*)d_in[5];
  const float* Wv = (const float*)d_in[6];
  const float* bv = (const float*)d_in[7];
  float* out = (float*)d_out;

  char* ws = (char*)d_ws;
  float*  enc = (float*)(ws);                              // 1 MB
  float*  dec = (float*)(ws + (1u<<20));                   // 256 KB
  __bf16* WvT = (__bf16*)(ws + (2u<<20));                  // 8 MB
  __bf16* h   = (__bf16*)(ws + (10u<<20));                 // 32 MB (total 42 MB)

  encdec_kernel<<<BT_ + BU_, 256, 0, stream>>>(v, t, W1, b1, W2, b2, enc, dec);
  wv_transpose_kernel<<<1024, 256, 0, stream>>>(Wv, WvT);
  build_h_kernel<<<(M_*D_/8)/256, 256, 0, stream>>>(enc, dec, h);
  fused_lsm_kernel<<<M_/BM, 512, 0, stream>>>(h, WvT, bv, out);
}